// Round 13
// baseline (1438.052 us; speedup 1.0000x reference)
//
#include <hip/hip_runtime.h>
#include <math.h>

// ---------------------------------------------------------------------------
// GTAN2 R13: column-sliced XCD-pinned gather. k_gather: 4 slices x 32 cols;
// slice = (bid&7)>>1 pins each slice to 2 XCDs -> 3.2MB table slice is
// L2-resident; 1 row/wave, 4-edge quarter-wave parallelism w/ shfl broadcast;
// w1 recomputed per slice in-register (no w1s pass). k_gemm (R11) separate
// again: reads gbuf only -> single h/h1a buffers, no ping-pong.
// fc1/xdots/prep/fc2/CSR unchanged from R12.
// ---------------------------------------------------------------------------

typedef __attribute__((ext_vector_type(8))) short short8;
typedef __attribute__((ext_vector_type(4))) float f32x4;
#define MFMA16 __builtin_amdgcn_mfma_f32_16x16x32_bf16

__device__ __forceinline__ float lrelu02(float v) { return v > 0.f ? v : 0.2f * v; }

__device__ __forceinline__ float2 bf2f2(unsigned int v) {
    return make_float2(__uint_as_float(v << 16), __uint_as_float(v & 0xffff0000u));
}
__device__ __forceinline__ unsigned int f2bf(float f) {  // RNE bf16
    unsigned int u = __float_as_uint(f);
    u += 0x7fffu + ((u >> 16) & 1u);
    return u >> 16;
}
__device__ __forceinline__ float hi_part(float f) {
    return __uint_as_float(__float_as_uint(f) & 0xffff0000u);
}
__device__ __forceinline__ uint4 pack_hi(const float4& a, const float4& b) {
    uint4 r;
    r.x = (__float_as_uint(a.x) >> 16) | (__float_as_uint(a.y) & 0xffff0000u);
    r.y = (__float_as_uint(a.z) >> 16) | (__float_as_uint(a.w) & 0xffff0000u);
    r.z = (__float_as_uint(b.x) >> 16) | (__float_as_uint(b.y) & 0xffff0000u);
    r.w = (__float_as_uint(b.z) >> 16) | (__float_as_uint(b.w) & 0xffff0000u);
    return r;
}
__device__ __forceinline__ uint4 pack_lo(const float4& a, const float4& b) {
    uint4 r;
    r.x = f2bf(a.x - hi_part(a.x)) | (f2bf(a.y - hi_part(a.y)) << 16);
    r.y = f2bf(a.z - hi_part(a.z)) | (f2bf(a.w - hi_part(a.w)) << 16);
    r.z = f2bf(b.x - hi_part(b.x)) | (f2bf(b.y - hi_part(b.y)) << 16);
    r.w = f2bf(b.z - hi_part(b.z)) | (f2bf(b.w - hi_part(b.w)) << 16);
    return r;
}

// ---------------- CSR build ----------------
__global__ __launch_bounds__(256) void k_count(const int* __restrict__ s, int* __restrict__ cnt, int E) {
    int e = blockIdx.x * 256 + threadIdx.x;
    if (e < E) atomicAdd(&cnt[s[e]], 1);
}

__global__ __launch_bounds__(256) void k_scan1(const int* __restrict__ cnt, int* __restrict__ bs, int N) {
    __shared__ int sh[256];
    int idx = blockIdx.x * 256 + threadIdx.x;
    sh[threadIdx.x] = (idx < N) ? cnt[idx] : 0;
    __syncthreads();
#pragma unroll
    for (int off = 128; off; off >>= 1) {
        if (threadIdx.x < off) sh[threadIdx.x] += sh[threadIdx.x + off];
        __syncthreads();
    }
    if (threadIdx.x == 0) bs[blockIdx.x] = sh[0];
}

__global__ __launch_bounds__(256) void k_scan2(int* __restrict__ bs, int G) {
    __shared__ int sh[256];
    int t = threadIdx.x;
    int v = (t < G) ? bs[t] : 0;
    sh[t] = v;
    __syncthreads();
    int val = v;
#pragma unroll
    for (int off = 1; off < 256; off <<= 1) {
        int o = (t >= off) ? sh[t - off] : 0;
        __syncthreads();
        val += o; sh[t] = val;
        __syncthreads();
    }
    if (t < G) bs[t] = val - v;  // exclusive
}

__global__ __launch_bounds__(256) void k_scan3(const int* __restrict__ cnt, const int* __restrict__ bs,
                                               int* __restrict__ rp, int N) {
    __shared__ int sh[256];
    int t = threadIdx.x;
    int idx = blockIdx.x * 256 + t;
    int v = (idx < N) ? cnt[idx] : 0;
    sh[t] = v;
    __syncthreads();
    int val = v;
#pragma unroll
    for (int off = 1; off < 256; off <<= 1) {
        int o = (t >= off) ? sh[t - off] : 0;
        __syncthreads();
        val += o; sh[t] = val;
        __syncthreads();
    }
    if (idx <= N) rp[idx] = val - v + bs[blockIdx.x];
}

__global__ __launch_bounds__(256) void k_scatter(const int* __restrict__ s, const int* __restrict__ t,
                                                 const int* __restrict__ rp, int* __restrict__ cursor,
                                                 int* __restrict__ t_sorted, int E) {
    int e = blockIdx.x * 256 + threadIdx.x;
    if (e < E) {
        int u = s[e];
        int pos = atomicAdd(&cursor[u], 1);
        t_sorted[rp[u] + pos] = t[e];
    }
}

// ---------------- W split ----------------
__global__ __launch_bounds__(256) void k_wsplit(const float* __restrict__ W,
                                                unsigned short* __restrict__ Whi,
                                                unsigned short* __restrict__ Wlo, int total) {
    int i = blockIdx.x * 256 + threadIdx.x;
    if (i < total) {
        float f = W[i];
        unsigned int u = __float_as_uint(f);
        Whi[i] = (unsigned short)(u >> 16);
        Wlo[i] = (unsigned short)f2bf(f - __uint_as_float(u & 0xffff0000u));
    }
}

// ---------------- k_prep: V vectors (W^T a1, W^T a2) + constants ------------
__global__ __launch_bounds__(256) void k_prep(
    const float* __restrict__ fcsW, const float* __restrict__ fcsb,
    const float* __restrict__ a1, const float* __restrict__ a2,
    float* __restrict__ Vf, unsigned short* __restrict__ Vh,
    unsigned short* __restrict__ Vl, float* __restrict__ cvec) {
    int i = blockIdx.x;
    int t = threadIdx.x;
    const float* W = fcsW + (size_t)i * 16384;
    if (t < 128) {
        float s1 = 0.f, s2 = 0.f;
        for (int j = 0; j < 128; ++j) {
            float w = W[j * 128 + t];
            s1 = fmaf(w, a1[i * 128 + j], s1);
            s2 = fmaf(w, a2[i * 128 + j], s2);
        }
        Vf[i * 128 + t] = s1;
        Vf[(16 + i) * 128 + t] = s2;
        Vh[i * 128 + t] = (unsigned short)(__float_as_uint(s1) >> 16);
        Vl[i * 128 + t] = (unsigned short)f2bf(s1 - hi_part(s1));
        Vh[(16 + i) * 128 + t] = (unsigned short)(__float_as_uint(s2) >> 16);
        Vl[(16 + i) * 128 + t] = (unsigned short)f2bf(s2 - hi_part(s2));
    } else if (t == 128) {
        float c1 = 0.f, c2 = 0.f;
        for (int j = 0; j < 128; ++j) {
            c1 = fmaf(fcsb[i * 128 + j], a1[i * 128 + j], c1);
            c2 = fmaf(fcsb[i * 128 + j], a2[i * 128 + j], c2);
        }
        cvec[i] = c1;
        cvec[16 + i] = c2;
    }
}

// ---------------- fc1: 3-term, BM=64, staged dense stores ----------------
__global__ __launch_bounds__(256) void k_fc1(
    const float* __restrict__ Xf,
    const unsigned short* __restrict__ Wh, const unsigned short* __restrict__ Wl,
    const float* __restrict__ bias,
    unsigned short* __restrict__ Yhi, unsigned short* __restrict__ Ylo, int N) {
    __shared__ unsigned short Shi[64 * 128];
    __shared__ unsigned short Slo[64 * 128];
    const int tid = threadIdx.x;
    const int r0 = blockIdx.x * 64;
    const int lane = tid & 63;
    const int w = tid >> 6;
    const int wr = (w >> 1) * 32, wc = (w & 1) * 64;
    const int frow = lane & 15;
    const int fk = lane >> 4;
    const int q4 = lane >> 4;

    f32x4 acc[2][4];
#pragma unroll
    for (int i = 0; i < 2; ++i)
#pragma unroll
        for (int j = 0; j < 4; ++j) acc[i][j] = (f32x4){0.f, 0.f, 0.f, 0.f};

    const float4 z4 = make_float4(0.f, 0.f, 0.f, 0.f);
#pragma unroll
    for (int kc = 0; kc < 8; ++kc) {
        short8 ah[2], al[2];
#pragma unroll
        for (int ri = 0; ri < 2; ++ri) {
            int row = r0 + wr + ri * 16 + frow;
            float4 va = z4, vb = z4;
            if (row < N) {
                const float* p = Xf + (size_t)row * 256 + kc * 32 + fk * 8;
                va = *(const float4*)p;
                vb = *(const float4*)(p + 4);
            }
            uint4 h = pack_hi(va, vb);
            uint4 l = pack_lo(va, vb);
            ah[ri] = *(short8*)&h;
            al[ri] = *(short8*)&l;
        }
#pragma unroll
        for (int ci = 0; ci < 4; ++ci) {
            int col = wc + ci * 16 + frow;
            short8 bh = *(const short8*)(Wh + (size_t)col * 256 + kc * 32 + fk * 8);
            short8 bl = *(const short8*)(Wl + (size_t)col * 256 + kc * 32 + fk * 8);
#pragma unroll
            for (int ri = 0; ri < 2; ++ri) {
                acc[ri][ci] = MFMA16(ah[ri], bh, acc[ri][ci], 0, 0, 0);
                acc[ri][ci] = MFMA16(ah[ri], bl, acc[ri][ci], 0, 0, 0);
                acc[ri][ci] = MFMA16(al[ri], bh, acc[ri][ci], 0, 0, 0);
            }
        }
    }

#pragma unroll
    for (int ci = 0; ci < 4; ++ci) {
        int col = wc + ci * 16 + frow;
        float bcol = bias[col];
#pragma unroll
        for (int ri = 0; ri < 2; ++ri) {
            f32x4 v = acc[ri][ci];
#pragma unroll
            for (int reg = 0; reg < 4; ++reg) {
                float val = fmaxf(v[reg] + bcol, 0.f);
                int row = wr + ri * 16 + q4 * 4 + reg;
                int dw = (col >> 1) ^ ((row & 12) << 1);
                Shi[row * 128 + dw * 2 + (col & 1)] = (unsigned short)(__float_as_uint(val) >> 16);
                Slo[row * 128 + dw * 2 + (col & 1)] = (unsigned short)f2bf(val - hi_part(val));
            }
        }
    }
    __syncthreads();
#pragma unroll
    for (int q = 0; q < 4; ++q) {
        int idx = q * 256 + tid;
        int row = idx >> 4;
        int gc = idx & 15;
        int dwb = (gc * 4) ^ ((row & 12) << 1);
        int grow = r0 + row;
        if (grow < N) {
            *(uint4*)(Yhi + (size_t)grow * 128 + gc * 8) = *(const uint4*)(Shi + row * 128 + dwb * 2);
            *(uint4*)(Ylo + (size_t)grow * 128 + gc * 8) = *(const uint4*)(Slo + row * 128 + dwb * 2);
        }
    }
}

// ---------------- k_xdots: x1a/xa2a for ALL hops in one N x 32 GEMM ---------
__global__ __launch_bounds__(256) void k_xdots(
    const unsigned short* __restrict__ Xhi, const unsigned short* __restrict__ Xlo,
    const unsigned short* __restrict__ Vh, const unsigned short* __restrict__ Vl,
    const float* __restrict__ cvec,
    float* __restrict__ x1a_all, float* __restrict__ xa2a_all, int N) {
    const int tid = threadIdx.x;
    const int r0 = blockIdx.x * 64;
    const int lane = tid & 63;
    const int w = tid >> 6;
    const int wr = w * 16;
    const int frow = lane & 15;
    const int fk = lane >> 4;
    const int q4 = lane >> 4;

    f32x4 acc[2];
    acc[0] = (f32x4){0.f, 0.f, 0.f, 0.f};
    acc[1] = (f32x4){0.f, 0.f, 0.f, 0.f};

    const short8 z8 = (short8){0, 0, 0, 0, 0, 0, 0, 0};
#pragma unroll
    for (int kc = 0; kc < 4; ++kc) {
        int row = r0 + wr + frow;
        bool ok = row < N;
        short8 ah = ok ? *(const short8*)(Xhi + (size_t)row * 128 + kc * 32 + fk * 8) : z8;
        short8 al = ok ? *(const short8*)(Xlo + (size_t)row * 128 + kc * 32 + fk * 8) : z8;
#pragma unroll
        for (int ci = 0; ci < 2; ++ci) {
            int col = ci * 16 + frow;
            short8 bh = *(const short8*)(Vh + (size_t)col * 128 + kc * 32 + fk * 8);
            short8 bl = *(const short8*)(Vl + (size_t)col * 128 + kc * 32 + fk * 8);
            acc[ci] = MFMA16(ah, bh, acc[ci], 0, 0, 0);
            acc[ci] = MFMA16(ah, bl, acc[ci], 0, 0, 0);
            acc[ci] = MFMA16(al, bh, acc[ci], 0, 0, 0);
        }
    }

#pragma unroll
    for (int ci = 0; ci < 2; ++ci) {
        int col = ci * 16 + frow;
        float c = cvec[col];
#pragma unroll
        for (int reg = 0; reg < 4; ++reg) {
            int grow = r0 + wr + q4 * 4 + reg;
            if (grow < N) {
                float val = acc[ci][reg] + c;
                if (col < 10) x1a_all[(size_t)col * N + grow] = val;
                else if (col >= 16 && col < 26) xa2a_all[(size_t)(col - 16) * N + grow] = val;
            }
        }
    }
}

// ---------------- k_gather: column-sliced, XCD-pinned, 1 row/wave -----------
// slice = (bid&7)>>1 (pins 3.2MB table slice to 2 XCDs); rowgroup of 4 rows
// per block (1 per wave); quarter-waves process 4 edges concurrently with
// shfl-broadcast (w,t); per-edge slice read = 64B = one sector.
__global__ __launch_bounds__(256) void k_gather(
    const unsigned short* __restrict__ table, const unsigned short* __restrict__ xh,
    const float* __restrict__ x1a, const float* __restrict__ xa2a,
    const float* __restrict__ h1in,
    const int* __restrict__ rp, const int* __restrict__ ts,
    unsigned short* __restrict__ gout, int N, int RG) {
    const int r = (int)blockIdx.x & 7;
    const int qb = (int)blockIdx.x >> 3;
    const int slice = r >> 1;
    const int rg = qb * 2 + (r & 1);
    if (rg >= RG) return;
    const int wid = threadIdx.x >> 6;
    const int lane = threadIdx.x & 63;
    const int u = rg * 4 + wid;
    if (u >= N) return;
    const int m = lane & 15;
    const int qw = lane >> 4;

    float x1u = x1a[u];
    float w2 = expf(lrelu02(x1u + xa2a[u]));
    float accx = 0.f, accy = 0.f, divp = 0.f;
    int p0 = rp[u], p1 = rp[u + 1];
    for (int base = p0; base < p1; base += 64) {
        int e = base + lane;
        int tv = 0;
        float wv = 0.f;
        if (e < p1) {
            tv = ts[e];
            wv = expf(lrelu02(x1u + h1in[tv]));
        }
        divp += wv;
        int mm = p1 - base; if (mm > 64) mm = 64;
        for (int j = 0; j < mm; j += 4) {
            int jj = j + qw;
            float w = __shfl(wv, jj & 63, 64);
            int tt = __shfl(tv, jj & 63, 64);
            if (jj >= mm) w = 0.f;
            unsigned int hv = *(const unsigned int*)(table + (size_t)tt * 128 + slice * 32 + m * 2);
            float2 f = bf2f2(hv);
            accx = fmaf(w, f.x, accx);
            accy = fmaf(w, f.y, accy);
        }
    }
#pragma unroll
    for (int o = 1; o < 64; o <<= 1) divp += __shfl_xor(divp, o, 64);
    accx += __shfl_xor(accx, 16, 64); accx += __shfl_xor(accx, 32, 64);
    accy += __shfl_xor(accy, 16, 64); accy += __shfl_xor(accy, 32, 64);
    float rdiv = 1.f / (divp + w2);
    unsigned int xv = *(const unsigned int*)(xh + (size_t)u * 128 + slice * 32 + m * 2);
    float2 xf = bf2f2(xv);
    float gx = rdiv * (accx + w2 * xf.x);
    float gy = rdiv * (accy + w2 * xf.y);
    if (qw == 0)
        *(unsigned int*)(gout + (size_t)u * 128 + slice * 32 + m * 2) = f2bf(gx) | (f2bf(gy) << 16);
}

// ---------------- k_gemm: h_next = elu(g @ W^T + b), fused h1a dot ----------
__global__ __launch_bounds__(256) void k_gemm(
    const unsigned short* __restrict__ G,
    const unsigned short* __restrict__ Wh, const unsigned short* __restrict__ Wl,
    const float* __restrict__ bias, const float* __restrict__ vnext,
    const float* __restrict__ cnextp,
    unsigned short* __restrict__ Hout, float* __restrict__ h1a, int N) {
    __shared__ unsigned short So[64 * 128];  // 16 KB C-stage
    __shared__ float dotbuf[64][2];
    const int tid = threadIdx.x;
    const int r0 = blockIdx.x * 64;
    const int lane = tid & 63;
    const int w = tid >> 6;
    const int wr = (w >> 1) * 32, wc = (w & 1) * 64;
    const int frow = lane & 15;
    const int fk = lane >> 4;
    const int q4 = lane >> 4;
    const bool dodot = vnext != nullptr;

    f32x4 acc[2][4];
#pragma unroll
    for (int i = 0; i < 2; ++i)
#pragma unroll
        for (int j = 0; j < 4; ++j) acc[i][j] = (f32x4){0.f, 0.f, 0.f, 0.f};

    const short8 z8 = (short8){0, 0, 0, 0, 0, 0, 0, 0};
#pragma unroll
    for (int kc = 0; kc < 4; ++kc) {
        short8 ah[2];
#pragma unroll
        for (int ri = 0; ri < 2; ++ri) {
            int row = r0 + wr + ri * 16 + frow;
            ah[ri] = (row < N) ? *(const short8*)(G + (size_t)row * 128 + kc * 32 + fk * 8) : z8;
        }
#pragma unroll
        for (int ci = 0; ci < 4; ++ci) {
            int col = wc + ci * 16 + frow;
            short8 bh = *(const short8*)(Wh + (size_t)col * 128 + kc * 32 + fk * 8);
            short8 bl = *(const short8*)(Wl + (size_t)col * 128 + kc * 32 + fk * 8);
#pragma unroll
            for (int ri = 0; ri < 2; ++ri) {
                acc[ri][ci] = MFMA16(ah[ri], bh, acc[ri][ci], 0, 0, 0);
                acc[ri][ci] = MFMA16(ah[ri], bl, acc[ri][ci], 0, 0, 0);
            }
        }
    }

    float dotA[2][4] = {};
#pragma unroll
    for (int ci = 0; ci < 4; ++ci) {
        int col = wc + ci * 16 + frow;
        float bcol = bias[col];
        float vc = dodot ? vnext[col] : 0.f;
#pragma unroll
        for (int ri = 0; ri < 2; ++ri) {
            f32x4 v = acc[ri][ci];
#pragma unroll
            for (int reg = 0; reg < 4; ++reg) {
                float val = v[reg] + bcol;
                val = val > 0.f ? val : expf(val) - 1.f;  // elu
                int row = wr + ri * 16 + q4 * 4 + reg;
                int dw = (col >> 1) ^ ((row & 12) << 1);
                So[row * 128 + dw * 2 + (col & 1)] = (unsigned short)f2bf(val);
                dotA[ri][reg] = fmaf(val, vc, dotA[ri][reg]);
            }
        }
    }
#pragma unroll
    for (int mm = 1; mm < 16; mm <<= 1)
#pragma unroll
        for (int ri = 0; ri < 2; ++ri)
#pragma unroll
            for (int reg = 0; reg < 4; ++reg)
                dotA[ri][reg] += __shfl_xor(dotA[ri][reg], mm, 64);
    if (frow == 0) {
#pragma unroll
        for (int ri = 0; ri < 2; ++ri)
#pragma unroll
            for (int reg = 0; reg < 4; ++reg) {
                int rl = wr + ri * 16 + q4 * 4 + reg;
                dotbuf[rl][w & 1] = dotA[ri][reg];
            }
    }
    __syncthreads();

#pragma unroll
    for (int q = 0; q < 4; ++q) {
        int idx = q * 256 + tid;
        int row = idx >> 4;
        int gc = idx & 15;
        int dwb = (gc * 4) ^ ((row & 12) << 1);
        uint4 vv = *(const uint4*)(So + row * 128 + dwb * 2);
        int grow = r0 + row;
        if (grow < N) *(uint4*)(Hout + (size_t)grow * 128 + gc * 8) = vv;
    }
    if (dodot && tid < 64) {
        int grow = r0 + tid;
        if (grow < N) h1a[grow] = dotbuf[tid][0] + dotbuf[tid][1] + cnextp[0];
    }
}

// ---------------- fc2: barrier-free, zero-LDS, 2-term, BM=64 ----------------
__global__ __launch_bounds__(256) void k_fc2(
    const unsigned short* __restrict__ Xhi,
    const unsigned short* __restrict__ Wh, const unsigned short* __restrict__ Wl,
    const float* __restrict__ bias, float* __restrict__ Yf, int N) {
    const int tid = threadIdx.x;
    const int r0 = blockIdx.x * 64;
    const int lane = tid & 63;
    const int w = tid >> 6;
    const int wr = w * 16;
    const int frow = lane & 15;
    const int fk = lane >> 4;
    const int q4 = lane >> 4;

    f32x4 acc[4];
#pragma unroll
    for (int j = 0; j < 4; ++j) acc[j] = (f32x4){0.f, 0.f, 0.f, 0.f};

    const short8 z8 = (short8){0, 0, 0, 0, 0, 0, 0, 0};
#pragma unroll
    for (int kc = 0; kc < 4; ++kc) {
        int row = r0 + wr + frow;
        short8 ah = (row < N) ? *(const short8*)(Xhi + (size_t)row * 128 + kc * 32 + fk * 8) : z8;
#pragma unroll
        for (int ci = 0; ci < 4; ++ci) {
            int col = ci * 16 + frow;
            short8 bh = *(const short8*)(Wh + (size_t)col * 128 + kc * 32 + fk * 8);
            short8 bl = *(const short8*)(Wl + (size_t)col * 128 + kc * 32 + fk * 8);
            acc[ci] = MFMA16(ah, bh, acc[ci], 0, 0, 0);
            acc[ci] = MFMA16(ah, bl, acc[ci], 0, 0, 0);
        }
    }

#pragma unroll
    for (int ci = 0; ci < 4; ++ci) {
        int col = ci * 16 + frow;
        float bcol = bias[col];
#pragma unroll
        for (int reg = 0; reg < 4; ++reg) {
            int grow = r0 + wr + q4 * 4 + reg;
            if (grow < N) Yf[(size_t)grow * 64 + col] = acc[ci][reg] + bcol;
        }
    }
}

// ---------------- launch ----------------
extern "C" void kernel_launch(void* const* d_in, const int* in_sizes, int n_in,
                              void* d_out, int out_size, void* d_ws, size_t ws_size,
                              hipStream_t stream) {
    const float* x_in = (const float*)d_in[0];
    const int*   s    = (const int*)d_in[1];
    const int*   t    = (const int*)d_in[2];
    const float* fc1W = (const float*)d_in[3];
    const float* fc1b = (const float*)d_in[4];
    const float* fcsW = (const float*)d_in[5];
    const float* fcsb = (const float*)d_in[6];
    const float* a1   = (const float*)d_in[7];
    const float* a2   = (const float*)d_in[8];
    const float* fc2W = (const float*)d_in[9];
    const float* fc2b = (const float*)d_in[10];

    const int N = in_sizes[0] / 256;  // 50000
    const int E = in_sizes[1];        // 800000
    const int G = (N + 255) / 256;
    const int NB64 = (N + 63) / 64;   // 782
    const int RG = (N + 3) / 4;       // 12500 rowgroups
    const int GGRID = 8 * ((RG + 1) / 2);  // 50000 gather blocks

    char* ws = (char*)d_ws;
    size_t off = 0;
    auto alloc = [&](size_t bytes) -> void* {
        void* p = ws + off;
        off += (bytes + 255) & ~(size_t)255;
        return p;
    };
    unsigned short* xbuf_hi = (unsigned short*)alloc((size_t)N * 128 * 2);
    unsigned short* xbuf_lo = (unsigned short*)alloc((size_t)N * 128 * 2);
    unsigned short* hbuf    = (unsigned short*)alloc((size_t)N * 128 * 2);
    unsigned short* gbuf    = (unsigned short*)alloc((size_t)N * 128 * 2);
    unsigned short* Whi  = (unsigned short*)alloc((size_t)10 * 16384 * 2);
    unsigned short* Wlo  = (unsigned short*)alloc((size_t)10 * 16384 * 2);
    unsigned short* W1hi = (unsigned short*)alloc((size_t)128 * 256 * 2);
    unsigned short* W1lo = (unsigned short*)alloc((size_t)128 * 256 * 2);
    unsigned short* W2hi = (unsigned short*)alloc((size_t)64 * 128 * 2);
    unsigned short* W2lo = (unsigned short*)alloc((size_t)64 * 128 * 2);
    float* Vf   = (float*)alloc((size_t)32 * 128 * 4);
    unsigned short* Vh = (unsigned short*)alloc((size_t)32 * 128 * 2);
    unsigned short* Vl = (unsigned short*)alloc((size_t)32 * 128 * 2);
    float* cvec = (float*)alloc((size_t)32 * 4);
    float* x1a_all  = (float*)alloc((size_t)10 * N * 4);
    float* xa2a_all = (float*)alloc((size_t)10 * N * 4);
    float* h1a  = (float*)alloc((size_t)N * 4);
    int* row_ptr  = (int*)alloc((size_t)(N + 1) * 4);
    int* cnt      = (int*)alloc((size_t)N * 4);
    int* bsums    = (int*)alloc((size_t)1024);
    int* t_sorted = (int*)alloc((size_t)E * 4);

    // CSR build
    hipMemsetAsync(cnt, 0, (size_t)N * 4, stream);
    k_count<<<(E + 255) / 256, 256, 0, stream>>>(s, cnt, E);
    k_scan1<<<G, 256, 0, stream>>>(cnt, bsums, N);
    k_scan2<<<1, 256, 0, stream>>>(bsums, G);
    k_scan3<<<G, 256, 0, stream>>>(cnt, bsums, row_ptr, N);
    hipMemsetAsync(cnt, 0, (size_t)N * 4, stream);
    k_scatter<<<(E + 255) / 256, 256, 0, stream>>>(s, t, row_ptr, cnt, t_sorted, E);

    // W splits + V prep
    k_wsplit<<<(10 * 16384 + 255) / 256, 256, 0, stream>>>(fcsW, Whi, Wlo, 10 * 16384);
    k_wsplit<<<(128 * 256 + 255) / 256, 256, 0, stream>>>(fc1W, W1hi, W1lo, 128 * 256);
    k_wsplit<<<(64 * 128 + 255) / 256, 256, 0, stream>>>(fc2W, W2hi, W2lo, 64 * 128);
    hipMemsetAsync(Vf, 0, (size_t)32 * 128 * 4, stream);
    hipMemsetAsync(Vh, 0, (size_t)32 * 128 * 2, stream);
    hipMemsetAsync(Vl, 0, (size_t)32 * 128 * 2, stream);
    hipMemsetAsync(cvec, 0, (size_t)32 * 4, stream);
    k_prep<<<10, 256, 0, stream>>>(fcsW, fcsb, a1, a2, Vf, Vh, Vl, cvec);

    // fc1 + relu -> split planes
    k_fc1<<<NB64, 256, 0, stream>>>(x_in, W1hi, W1lo, fc1b, xbuf_hi, xbuf_lo, N);

    // x-side scalars for all hops
    k_xdots<<<NB64, 256, 0, stream>>>(xbuf_hi, xbuf_lo, Vh, Vl, cvec,
                                      x1a_all, xa2a_all, N);

    // hops: sliced gather -> GEMM (single h/h1a buffers; k_gemm reads gbuf only)
    const unsigned short* table = xbuf_hi;
    const float* h1in = xa2a_all;  // hop 0: h1 == xa2 (h == x)
    for (int i = 0; i < 10; ++i) {
        k_gather<<<GGRID, 256, 0, stream>>>(table, xbuf_hi,
                                            x1a_all + (size_t)i * N, xa2a_all + (size_t)i * N,
                                            h1in, row_ptr, t_sorted, gbuf, N, RG);
        const float* vnext = (i < 9) ? (Vf + (size_t)(16 + i + 1) * 128) : nullptr;
        k_gemm<<<NB64, 256, 0, stream>>>(gbuf, Whi + (size_t)i * 16384,
                                         Wlo + (size_t)i * 16384,
                                         fcsb + (size_t)i * 128, vnext, cvec + (16 + i + 1),
                                         hbuf, h1a, N);
        table = hbuf;
        h1in = h1a;
    }

    // fc2
    k_fc2<<<NB64, 256, 0, stream>>>(table, W2hi, W2lo, fc2b, (float*)d_out, N);
}

// Round 14
// 1104.131 us; speedup vs baseline: 1.3024x; 1.3024x over previous
//
#include <hip/hip_runtime.h>
#include <math.h>

// ---------------------------------------------------------------------------
// GTAN2 R14: R12 structure restored (R13's sliced gather regressed: 4x index
// re-read + 4x exp + no real XCD pinning). k_hop phase 1 now processes rows
// in PAIRS (j, j+8) with interleaved edge batches: 2 independent dependency
// chains per wave, 16 table loads in flight (was 8), serial row passes 16->8.
// All else identical to R12 (790us baseline).
// ---------------------------------------------------------------------------

typedef __attribute__((ext_vector_type(8))) short short8;
typedef __attribute__((ext_vector_type(4))) float f32x4;
#define MFMA16 __builtin_amdgcn_mfma_f32_16x16x32_bf16

__device__ __forceinline__ float lrelu02(float v) { return v > 0.f ? v : 0.2f * v; }

__device__ __forceinline__ float2 bf2f2(unsigned int v) {
    return make_float2(__uint_as_float(v << 16), __uint_as_float(v & 0xffff0000u));
}
__device__ __forceinline__ unsigned int f2bf(float f) {  // RNE bf16
    unsigned int u = __float_as_uint(f);
    u += 0x7fffu + ((u >> 16) & 1u);
    return u >> 16;
}
__device__ __forceinline__ float hi_part(float f) {
    return __uint_as_float(__float_as_uint(f) & 0xffff0000u);
}
__device__ __forceinline__ uint4 pack_hi(const float4& a, const float4& b) {
    uint4 r;
    r.x = (__float_as_uint(a.x) >> 16) | (__float_as_uint(a.y) & 0xffff0000u);
    r.y = (__float_as_uint(a.z) >> 16) | (__float_as_uint(a.w) & 0xffff0000u);
    r.z = (__float_as_uint(b.x) >> 16) | (__float_as_uint(b.y) & 0xffff0000u);
    r.w = (__float_as_uint(b.z) >> 16) | (__float_as_uint(b.w) & 0xffff0000u);
    return r;
}
__device__ __forceinline__ uint4 pack_lo(const float4& a, const float4& b) {
    uint4 r;
    r.x = f2bf(a.x - hi_part(a.x)) | (f2bf(a.y - hi_part(a.y)) << 16);
    r.y = f2bf(a.z - hi_part(a.z)) | (f2bf(a.w - hi_part(a.w)) << 16);
    r.z = f2bf(b.x - hi_part(b.x)) | (f2bf(b.y - hi_part(b.y)) << 16);
    r.w = f2bf(b.z - hi_part(b.z)) | (f2bf(b.w - hi_part(b.w)) << 16);
    return r;
}

// ---------------- CSR build ----------------
__global__ __launch_bounds__(256) void k_count(const int* __restrict__ s, int* __restrict__ cnt, int E) {
    int e = blockIdx.x * 256 + threadIdx.x;
    if (e < E) atomicAdd(&cnt[s[e]], 1);
}

__global__ __launch_bounds__(256) void k_scan1(const int* __restrict__ cnt, int* __restrict__ bs, int N) {
    __shared__ int sh[256];
    int idx = blockIdx.x * 256 + threadIdx.x;
    sh[threadIdx.x] = (idx < N) ? cnt[idx] : 0;
    __syncthreads();
#pragma unroll
    for (int off = 128; off; off >>= 1) {
        if (threadIdx.x < off) sh[threadIdx.x] += sh[threadIdx.x + off];
        __syncthreads();
    }
    if (threadIdx.x == 0) bs[blockIdx.x] = sh[0];
}

__global__ __launch_bounds__(256) void k_scan2(int* __restrict__ bs, int G) {
    __shared__ int sh[256];
    int t = threadIdx.x;
    int v = (t < G) ? bs[t] : 0;
    sh[t] = v;
    __syncthreads();
    int val = v;
#pragma unroll
    for (int off = 1; off < 256; off <<= 1) {
        int o = (t >= off) ? sh[t - off] : 0;
        __syncthreads();
        val += o; sh[t] = val;
        __syncthreads();
    }
    if (t < G) bs[t] = val - v;  // exclusive
}

__global__ __launch_bounds__(256) void k_scan3(const int* __restrict__ cnt, const int* __restrict__ bs,
                                               int* __restrict__ rp, int N) {
    __shared__ int sh[256];
    int t = threadIdx.x;
    int idx = blockIdx.x * 256 + t;
    int v = (idx < N) ? cnt[idx] : 0;
    sh[t] = v;
    __syncthreads();
    int val = v;
#pragma unroll
    for (int off = 1; off < 256; off <<= 1) {
        int o = (t >= off) ? sh[t - off] : 0;
        __syncthreads();
        val += o; sh[t] = val;
        __syncthreads();
    }
    if (idx <= N) rp[idx] = val - v + bs[blockIdx.x];
}

__global__ __launch_bounds__(256) void k_scatter(const int* __restrict__ s, const int* __restrict__ t,
                                                 const int* __restrict__ rp, int* __restrict__ cursor,
                                                 int* __restrict__ t_sorted, int E) {
    int e = blockIdx.x * 256 + threadIdx.x;
    if (e < E) {
        int u = s[e];
        int pos = atomicAdd(&cursor[u], 1);
        t_sorted[rp[u] + pos] = t[e];
    }
}

// ---------------- W split ----------------
__global__ __launch_bounds__(256) void k_wsplit(const float* __restrict__ W,
                                                unsigned short* __restrict__ Whi,
                                                unsigned short* __restrict__ Wlo, int total) {
    int i = blockIdx.x * 256 + threadIdx.x;
    if (i < total) {
        float f = W[i];
        unsigned int u = __float_as_uint(f);
        Whi[i] = (unsigned short)(u >> 16);
        Wlo[i] = (unsigned short)f2bf(f - __uint_as_float(u & 0xffff0000u));
    }
}

// ---------------- k_prep: V vectors (W^T a1, W^T a2) + constants ------------
__global__ __launch_bounds__(256) void k_prep(
    const float* __restrict__ fcsW, const float* __restrict__ fcsb,
    const float* __restrict__ a1, const float* __restrict__ a2,
    float* __restrict__ Vf, unsigned short* __restrict__ Vh,
    unsigned short* __restrict__ Vl, float* __restrict__ cvec) {
    int i = blockIdx.x;
    int t = threadIdx.x;
    const float* W = fcsW + (size_t)i * 16384;
    if (t < 128) {
        float s1 = 0.f, s2 = 0.f;
        for (int j = 0; j < 128; ++j) {
            float w = W[j * 128 + t];
            s1 = fmaf(w, a1[i * 128 + j], s1);
            s2 = fmaf(w, a2[i * 128 + j], s2);
        }
        Vf[i * 128 + t] = s1;
        Vf[(16 + i) * 128 + t] = s2;
        Vh[i * 128 + t] = (unsigned short)(__float_as_uint(s1) >> 16);
        Vl[i * 128 + t] = (unsigned short)f2bf(s1 - hi_part(s1));
        Vh[(16 + i) * 128 + t] = (unsigned short)(__float_as_uint(s2) >> 16);
        Vl[(16 + i) * 128 + t] = (unsigned short)f2bf(s2 - hi_part(s2));
    } else if (t == 128) {
        float c1 = 0.f, c2 = 0.f;
        for (int j = 0; j < 128; ++j) {
            c1 = fmaf(fcsb[i * 128 + j], a1[i * 128 + j], c1);
            c2 = fmaf(fcsb[i * 128 + j], a2[i * 128 + j], c2);
        }
        cvec[i] = c1;
        cvec[16 + i] = c2;
    }
}

// ---------------- fc1: 3-term, BM=64, staged dense stores ----------------
__global__ __launch_bounds__(256) void k_fc1(
    const float* __restrict__ Xf,
    const unsigned short* __restrict__ Wh, const unsigned short* __restrict__ Wl,
    const float* __restrict__ bias,
    unsigned short* __restrict__ Yhi, unsigned short* __restrict__ Ylo, int N) {
    __shared__ unsigned short Shi[64 * 128];
    __shared__ unsigned short Slo[64 * 128];
    const int tid = threadIdx.x;
    const int r0 = blockIdx.x * 64;
    const int lane = tid & 63;
    const int w = tid >> 6;
    const int wr = (w >> 1) * 32, wc = (w & 1) * 64;
    const int frow = lane & 15;
    const int fk = lane >> 4;
    const int q4 = lane >> 4;

    f32x4 acc[2][4];
#pragma unroll
    for (int i = 0; i < 2; ++i)
#pragma unroll
        for (int j = 0; j < 4; ++j) acc[i][j] = (f32x4){0.f, 0.f, 0.f, 0.f};

    const float4 z4 = make_float4(0.f, 0.f, 0.f, 0.f);
#pragma unroll
    for (int kc = 0; kc < 8; ++kc) {
        short8 ah[2], al[2];
#pragma unroll
        for (int ri = 0; ri < 2; ++ri) {
            int row = r0 + wr + ri * 16 + frow;
            float4 va = z4, vb = z4;
            if (row < N) {
                const float* p = Xf + (size_t)row * 256 + kc * 32 + fk * 8;
                va = *(const float4*)p;
                vb = *(const float4*)(p + 4);
            }
            uint4 h = pack_hi(va, vb);
            uint4 l = pack_lo(va, vb);
            ah[ri] = *(short8*)&h;
            al[ri] = *(short8*)&l;
        }
#pragma unroll
        for (int ci = 0; ci < 4; ++ci) {
            int col = wc + ci * 16 + frow;
            short8 bh = *(const short8*)(Wh + (size_t)col * 256 + kc * 32 + fk * 8);
            short8 bl = *(const short8*)(Wl + (size_t)col * 256 + kc * 32 + fk * 8);
#pragma unroll
            for (int ri = 0; ri < 2; ++ri) {
                acc[ri][ci] = MFMA16(ah[ri], bh, acc[ri][ci], 0, 0, 0);
                acc[ri][ci] = MFMA16(ah[ri], bl, acc[ri][ci], 0, 0, 0);
                acc[ri][ci] = MFMA16(al[ri], bh, acc[ri][ci], 0, 0, 0);
            }
        }
    }

#pragma unroll
    for (int ci = 0; ci < 4; ++ci) {
        int col = wc + ci * 16 + frow;
        float bcol = bias[col];
#pragma unroll
        for (int ri = 0; ri < 2; ++ri) {
            f32x4 v = acc[ri][ci];
#pragma unroll
            for (int reg = 0; reg < 4; ++reg) {
                float val = fmaxf(v[reg] + bcol, 0.f);
                int row = wr + ri * 16 + q4 * 4 + reg;
                int dw = (col >> 1) ^ ((row & 12) << 1);
                Shi[row * 128 + dw * 2 + (col & 1)] = (unsigned short)(__float_as_uint(val) >> 16);
                Slo[row * 128 + dw * 2 + (col & 1)] = (unsigned short)f2bf(val - hi_part(val));
            }
        }
    }
    __syncthreads();
#pragma unroll
    for (int q = 0; q < 4; ++q) {
        int idx = q * 256 + tid;
        int row = idx >> 4;
        int gc = idx & 15;
        int dwb = (gc * 4) ^ ((row & 12) << 1);
        int grow = r0 + row;
        if (grow < N) {
            *(uint4*)(Yhi + (size_t)grow * 128 + gc * 8) = *(const uint4*)(Shi + row * 128 + dwb * 2);
            *(uint4*)(Ylo + (size_t)grow * 128 + gc * 8) = *(const uint4*)(Slo + row * 128 + dwb * 2);
        }
    }
}

// ---------------- k_xdots: x1a/xa2a for ALL hops in one N x 32 GEMM ---------
__global__ __launch_bounds__(256) void k_xdots(
    const unsigned short* __restrict__ Xhi, const unsigned short* __restrict__ Xlo,
    const unsigned short* __restrict__ Vh, const unsigned short* __restrict__ Vl,
    const float* __restrict__ cvec,
    float* __restrict__ x1a_all, float* __restrict__ xa2a_all, int N) {
    const int tid = threadIdx.x;
    const int r0 = blockIdx.x * 64;
    const int lane = tid & 63;
    const int w = tid >> 6;
    const int wr = w * 16;
    const int frow = lane & 15;
    const int fk = lane >> 4;
    const int q4 = lane >> 4;

    f32x4 acc[2];
    acc[0] = (f32x4){0.f, 0.f, 0.f, 0.f};
    acc[1] = (f32x4){0.f, 0.f, 0.f, 0.f};

    const short8 z8 = (short8){0, 0, 0, 0, 0, 0, 0, 0};
#pragma unroll
    for (int kc = 0; kc < 4; ++kc) {
        int row = r0 + wr + frow;
        bool ok = row < N;
        short8 ah = ok ? *(const short8*)(Xhi + (size_t)row * 128 + kc * 32 + fk * 8) : z8;
        short8 al = ok ? *(const short8*)(Xlo + (size_t)row * 128 + kc * 32 + fk * 8) : z8;
#pragma unroll
        for (int ci = 0; ci < 2; ++ci) {
            int col = ci * 16 + frow;
            short8 bh = *(const short8*)(Vh + (size_t)col * 128 + kc * 32 + fk * 8);
            short8 bl = *(const short8*)(Vl + (size_t)col * 128 + kc * 32 + fk * 8);
            acc[ci] = MFMA16(ah, bh, acc[ci], 0, 0, 0);
            acc[ci] = MFMA16(ah, bl, acc[ci], 0, 0, 0);
            acc[ci] = MFMA16(al, bh, acc[ci], 0, 0, 0);
        }
    }

#pragma unroll
    for (int ci = 0; ci < 2; ++ci) {
        int col = ci * 16 + frow;
        float c = cvec[col];
#pragma unroll
        for (int reg = 0; reg < 4; ++reg) {
            int grow = r0 + wr + q4 * 4 + reg;
            if (grow < N) {
                float val = acc[ci][reg] + c;
                if (col < 10) x1a_all[(size_t)col * N + grow] = val;
                else if (col >= 16 && col < 26) xa2a_all[(size_t)(col - 16) * N + grow] = val;
            }
        }
    }
}

// ---------------- k_hop: fused gather(2-row ILP) + GEMM + elu + h1 dot ------
__global__ __launch_bounds__(256) void k_hop(
    const unsigned short* __restrict__ table, const unsigned short* __restrict__ xh,
    const float* __restrict__ x1a, const float* __restrict__ xa2a,
    const float* __restrict__ h1in,
    const int* __restrict__ rp, const int* __restrict__ ts,
    const unsigned short* __restrict__ Wh, const unsigned short* __restrict__ Wl,
    const float* __restrict__ bias, const float* __restrict__ vnext,
    const float* __restrict__ cnextp,
    unsigned short* __restrict__ Hout, float* __restrict__ h1out, int N) {
    __shared__ unsigned short gS[64 * 128];  // 16 KB: g tile, then C-stage
    __shared__ uint2 ew[4][2][64];           // 4 KB: 2 row-slots per wave
    __shared__ float dotbuf[64][2];
    const int tid = threadIdx.x;
    const int wid = tid >> 6;
    const int lane = tid & 63;
    const int r0 = blockIdx.x * 64;

    // ---- phase 1: gather, rows processed in pairs (j, j+8) ----
    for (int j = 0; j < 8; ++j) {
        const int gr0 = wid * 16 + j;
        const int gr1 = gr0 + 8;
        const int u0 = r0 + gr0, u1 = r0 + gr1;
        const bool v0 = u0 < N, v1 = u1 < N;
        float x1u0 = v0 ? x1a[u0] : 0.f;
        float x1u1 = v1 ? x1a[u1] : 0.f;
        float w20 = v0 ? expf(lrelu02(x1u0 + xa2a[u0])) : 0.f;
        float w21 = v1 ? expf(lrelu02(x1u1 + xa2a[u1])) : 0.f;
        float a0x = 0.f, a0y = 0.f, d0 = 0.f;
        float a1x = 0.f, a1y = 0.f, d1 = 0.f;
        int c0 = v0 ? rp[u0] : 0, f0 = v0 ? rp[u0 + 1] : 0;
        int c1 = v1 ? rp[u1] : 0, f1 = v1 ? rp[u1 + 1] : 0;
        while (c0 < f0 || c1 < f1) {
            int m0 = f0 - c0; m0 = m0 < 0 ? 0 : (m0 > 64 ? 64 : m0);
            int m1 = f1 - c1; m1 = m1 < 0 ? 0 : (m1 > 64 ? 64 : m1);
            uint2 pk0 = make_uint2(0u, 0u), pk1 = make_uint2(0u, 0u);
            if (lane < m0) {
                int tv = ts[c0 + lane];
                pk0.x = (unsigned int)tv;
                pk0.y = __float_as_uint(expf(lrelu02(x1u0 + h1in[tv])));
            }
            if (lane < m1) {
                int tv = ts[c1 + lane];
                pk1.x = (unsigned int)tv;
                pk1.y = __float_as_uint(expf(lrelu02(x1u1 + h1in[tv])));
            }
            ew[wid][0][lane] = pk0;
            ew[wid][1][lane] = pk1;
            int mm = m0 > m1 ? m0 : m1;
            int m8 = (mm + 7) & ~7;
            for (int jj = 0; jj < m8; jj += 8) {
                uint2 q0[8], q1[8];
#pragma unroll
                for (int k = 0; k < 8; ++k) {
                    q0[k] = ew[wid][0][jj + k];
                    q1[k] = ew[wid][1][jj + k];
                }
                unsigned int hv0[8], hv1[8];
#pragma unroll
                for (int k = 0; k < 8; ++k) {
                    hv0[k] = *(const unsigned int*)(table + (size_t)q0[k].x * 128 + lane * 2);
                    hv1[k] = *(const unsigned int*)(table + (size_t)q1[k].x * 128 + lane * 2);
                }
#pragma unroll
                for (int k = 0; k < 8; ++k) {
                    float w0 = __uint_as_float(q0[k].y);
                    float w1v = __uint_as_float(q1[k].y);
                    float2 g0 = bf2f2(hv0[k]);
                    float2 g1 = bf2f2(hv1[k]);
                    a0x = fmaf(w0, g0.x, a0x); a0y = fmaf(w0, g0.y, a0y); d0 += w0;
                    a1x = fmaf(w1v, g1.x, a1x); a1y = fmaf(w1v, g1.y, a1y); d1 += w1v;
                }
            }
            c0 += 64; c1 += 64;
        }
        {
            unsigned int xv0 = v0 ? *(const unsigned int*)(xh + (size_t)u0 * 128 + lane * 2) : 0u;
            float2 xf0 = bf2f2(xv0);
            float rd0 = 1.f / (d0 + w20 + (v0 ? 0.f : 1.f));
            unsigned int p0 = f2bf(rd0 * (a0x + w20 * xf0.x)) | (f2bf(rd0 * (a0y + w20 * xf0.y)) << 16);
            int dw0 = (((lane >> 2) ^ (gr0 & 7)) << 2) | (lane & 3);
            *((unsigned int*)gS + gr0 * 64 + dw0) = p0;

            unsigned int xv1 = v1 ? *(const unsigned int*)(xh + (size_t)u1 * 128 + lane * 2) : 0u;
            float2 xf1 = bf2f2(xv1);
            float rd1 = 1.f / (d1 + w21 + (v1 ? 0.f : 1.f));
            unsigned int p1 = f2bf(rd1 * (a1x + w21 * xf1.x)) | (f2bf(rd1 * (a1y + w21 * xf1.y)) << 16);
            int dw1 = (((lane >> 2) ^ (gr1 & 7)) << 2) | (lane & 3);
            *((unsigned int*)gS + gr1 * 64 + dw1) = p1;
        }
    }
    __syncthreads();

    // ---- phase 2: GEMM ----
    const int w = wid;
    const int wr = (w >> 1) * 32, wc = (w & 1) * 64;
    const int frow = lane & 15;
    const int fk = lane >> 4;
    const int q4 = lane >> 4;
    const bool dodot = vnext != nullptr;

    f32x4 acc[2][4];
#pragma unroll
    for (int i = 0; i < 2; ++i)
#pragma unroll
        for (int j = 0; j < 4; ++j) acc[i][j] = (f32x4){0.f, 0.f, 0.f, 0.f};

#pragma unroll
    for (int kc = 0; kc < 4; ++kc) {
        short8 ah[2];
#pragma unroll
        for (int ri = 0; ri < 2; ++ri) {
            int row = wr + ri * 16 + frow;
            int gg = kc * 4 + fk;
            ah[ri] = *(const short8*)(gS + row * 128 + ((gg ^ (row & 7)) * 8));
        }
#pragma unroll
        for (int ci = 0; ci < 4; ++ci) {
            int col = wc + ci * 16 + frow;
            short8 bh = *(const short8*)(Wh + (size_t)col * 128 + kc * 32 + fk * 8);
            short8 bl = *(const short8*)(Wl + (size_t)col * 128 + kc * 32 + fk * 8);
#pragma unroll
            for (int ri = 0; ri < 2; ++ri) {
                acc[ri][ci] = MFMA16(ah[ri], bh, acc[ri][ci], 0, 0, 0);
                acc[ri][ci] = MFMA16(ah[ri], bl, acc[ri][ci], 0, 0, 0);
            }
        }
    }
    __syncthreads();  // all A-frag reads done; gS becomes C-stage

    float dotA[2][4] = {};
#pragma unroll
    for (int ci = 0; ci < 4; ++ci) {
        int col = wc + ci * 16 + frow;
        float bcol = bias[col];
        float vc = dodot ? vnext[col] : 0.f;
#pragma unroll
        for (int ri = 0; ri < 2; ++ri) {
            f32x4 v = acc[ri][ci];
#pragma unroll
            for (int reg = 0; reg < 4; ++reg) {
                float val = v[reg] + bcol;
                val = val > 0.f ? val : expf(val) - 1.f;  // elu
                int row = wr + ri * 16 + q4 * 4 + reg;
                int dw = (col >> 1) ^ ((row & 12) << 1);
                gS[row * 128 + dw * 2 + (col & 1)] = (unsigned short)f2bf(val);
                dotA[ri][reg] = fmaf(val, vc, dotA[ri][reg]);
            }
        }
    }
#pragma unroll
    for (int m = 1; m < 16; m <<= 1)
#pragma unroll
        for (int ri = 0; ri < 2; ++ri)
#pragma unroll
            for (int reg = 0; reg < 4; ++reg)
                dotA[ri][reg] += __shfl_xor(dotA[ri][reg], m, 64);
    if (frow == 0) {
#pragma unroll
        for (int ri = 0; ri < 2; ++ri)
#pragma unroll
            for (int reg = 0; reg < 4; ++reg) {
                int rl = wr + ri * 16 + q4 * 4 + reg;
                dotbuf[rl][w & 1] = dotA[ri][reg];
            }
    }
    __syncthreads();

#pragma unroll
    for (int q = 0; q < 4; ++q) {
        int idx = q * 256 + tid;        // 0..1023
        int row = idx >> 4;
        int gc = idx & 15;
        int dwb = (gc * 4) ^ ((row & 12) << 1);
        uint4 vv = *(const uint4*)(gS + row * 128 + dwb * 2);
        int grow = r0 + row;
        if (grow < N) *(uint4*)(Hout + (size_t)grow * 128 + gc * 8) = vv;
    }
    if (dodot && tid < 64) {
        int grow = r0 + tid;
        if (grow < N) h1out[grow] = dotbuf[tid][0] + dotbuf[tid][1] + cnextp[0];
    }
}

// ---------------- fc2: barrier-free, zero-LDS, 2-term, BM=64 ----------------
__global__ __launch_bounds__(256) void k_fc2(
    const unsigned short* __restrict__ Xhi,
    const unsigned short* __restrict__ Wh, const unsigned short* __restrict__ Wl,
    const float* __restrict__ bias, float* __restrict__ Yf, int N) {
    const int tid = threadIdx.x;
    const int r0 = blockIdx.x * 64;
    const int lane = tid & 63;
    const int w = tid >> 6;
    const int wr = w * 16;
    const int frow = lane & 15;
    const int fk = lane >> 4;
    const int q4 = lane >> 4;

    f32x4 acc[4];
#pragma unroll
    for (int j = 0; j < 4; ++j) acc[j] = (f32x4){0.f, 0.f, 0.f, 0.f};

    const short8 z8 = (short8){0, 0, 0, 0, 0, 0, 0, 0};
#pragma unroll
    for (int kc = 0; kc < 4; ++kc) {
        int row = r0 + wr + frow;
        short8 ah = (row < N) ? *(const short8*)(Xhi + (size_t)row * 128 + kc * 32 + fk * 8) : z8;
#pragma unroll
        for (int ci = 0; ci < 4; ++ci) {
            int col = ci * 16 + frow;
            short8 bh = *(const short8*)(Wh + (size_t)col * 128 + kc * 32 + fk * 8);
            short8 bl = *(const short8*)(Wl + (size_t)col * 128 + kc * 32 + fk * 8);
            acc[ci] = MFMA16(ah, bh, acc[ci], 0, 0, 0);
            acc[ci] = MFMA16(ah, bl, acc[ci], 0, 0, 0);
        }
    }

#pragma unroll
    for (int ci = 0; ci < 4; ++ci) {
        int col = ci * 16 + frow;
        float bcol = bias[col];
#pragma unroll
        for (int reg = 0; reg < 4; ++reg) {
            int grow = r0 + wr + q4 * 4 + reg;
            if (grow < N) Yf[(size_t)grow * 64 + col] = acc[ci][reg] + bcol;
        }
    }
}

// ---------------- launch ----------------
extern "C" void kernel_launch(void* const* d_in, const int* in_sizes, int n_in,
                              void* d_out, int out_size, void* d_ws, size_t ws_size,
                              hipStream_t stream) {
    const float* x_in = (const float*)d_in[0];
    const int*   s    = (const int*)d_in[1];
    const int*   t    = (const int*)d_in[2];
    const float* fc1W = (const float*)d_in[3];
    const float* fc1b = (const float*)d_in[4];
    const float* fcsW = (const float*)d_in[5];
    const float* fcsb = (const float*)d_in[6];
    const float* a1   = (const float*)d_in[7];
    const float* a2   = (const float*)d_in[8];
    const float* fc2W = (const float*)d_in[9];
    const float* fc2b = (const float*)d_in[10];

    const int N = in_sizes[0] / 256;  // 50000
    const int E = in_sizes[1];        // 800000
    const int G = (N + 255) / 256;
    const int NB64 = (N + 63) / 64;   // 782

    char* ws = (char*)d_ws;
    size_t off = 0;
    auto alloc = [&](size_t bytes) -> void* {
        void* p = ws + off;
        off += (bytes + 255) & ~(size_t)255;
        return p;
    };
    unsigned short* xbuf_hi = (unsigned short*)alloc((size_t)N * 128 * 2);
    unsigned short* xbuf_lo = (unsigned short*)alloc((size_t)N * 128 * 2);
    unsigned short* hA      = (unsigned short*)alloc((size_t)N * 128 * 2);
    unsigned short* hB      = (unsigned short*)alloc((size_t)N * 128 * 2);
    unsigned short* Whi  = (unsigned short*)alloc((size_t)10 * 16384 * 2);
    unsigned short* Wlo  = (unsigned short*)alloc((size_t)10 * 16384 * 2);
    unsigned short* W1hi = (unsigned short*)alloc((size_t)128 * 256 * 2);
    unsigned short* W1lo = (unsigned short*)alloc((size_t)128 * 256 * 2);
    unsigned short* W2hi = (unsigned short*)alloc((size_t)64 * 128 * 2);
    unsigned short* W2lo = (unsigned short*)alloc((size_t)64 * 128 * 2);
    float* Vf   = (float*)alloc((size_t)32 * 128 * 4);
    unsigned short* Vh = (unsigned short*)alloc((size_t)32 * 128 * 2);
    unsigned short* Vl = (unsigned short*)alloc((size_t)32 * 128 * 2);
    float* cvec = (float*)alloc((size_t)32 * 4);
    float* x1a_all  = (float*)alloc((size_t)10 * N * 4);
    float* xa2a_all = (float*)alloc((size_t)10 * N * 4);
    float* h1aA = (float*)alloc((size_t)N * 4);
    float* h1aB = (float*)alloc((size_t)N * 4);
    int* row_ptr  = (int*)alloc((size_t)(N + 1) * 4);
    int* cnt      = (int*)alloc((size_t)N * 4);
    int* bsums    = (int*)alloc((size_t)1024);
    int* t_sorted = (int*)alloc((size_t)E * 4);

    // CSR build
    hipMemsetAsync(cnt, 0, (size_t)N * 4, stream);
    k_count<<<(E + 255) / 256, 256, 0, stream>>>(s, cnt, E);
    k_scan1<<<G, 256, 0, stream>>>(cnt, bsums, N);
    k_scan2<<<1, 256, 0, stream>>>(bsums, G);
    k_scan3<<<G, 256, 0, stream>>>(cnt, bsums, row_ptr, N);
    hipMemsetAsync(cnt, 0, (size_t)N * 4, stream);
    k_scatter<<<(E + 255) / 256, 256, 0, stream>>>(s, t, row_ptr, cnt, t_sorted, E);

    // W splits + V prep
    k_wsplit<<<(10 * 16384 + 255) / 256, 256, 0, stream>>>(fcsW, Whi, Wlo, 10 * 16384);
    k_wsplit<<<(128 * 256 + 255) / 256, 256, 0, stream>>>(fc1W, W1hi, W1lo, 128 * 256);
    k_wsplit<<<(64 * 128 + 255) / 256, 256, 0, stream>>>(fc2W, W2hi, W2lo, 64 * 128);
    hipMemsetAsync(Vf, 0, (size_t)32 * 128 * 4, stream);
    hipMemsetAsync(Vh, 0, (size_t)32 * 128 * 2, stream);
    hipMemsetAsync(Vl, 0, (size_t)32 * 128 * 2, stream);
    hipMemsetAsync(cvec, 0, (size_t)32 * 4, stream);
    k_prep<<<10, 256, 0, stream>>>(fcsW, fcsb, a1, a2, Vf, Vh, Vl, cvec);

    // fc1 + relu -> split planes
    k_fc1<<<NB64, 256, 0, stream>>>(x_in, W1hi, W1lo, fc1b, xbuf_hi, xbuf_lo, N);

    // x-side scalars for all hops
    k_xdots<<<NB64, 256, 0, stream>>>(xbuf_hi, xbuf_lo, Vh, Vl, cvec,
                                      x1a_all, xa2a_all, N);

    // hops: fused gather + GEMM, ping-pong h / h1a
    const unsigned short* table = xbuf_hi;
    const float* h1in = xa2a_all;  // hop 0: h1 == xa2 (h == x)
    for (int i = 0; i < 10; ++i) {
        unsigned short* hout = (i & 1) ? hB : hA;
        float* h1out = (i & 1) ? h1aB : h1aA;
        const float* vnext = (i < 9) ? (Vf + (size_t)(16 + i + 1) * 128) : nullptr;
        k_hop<<<NB64, 256, 0, stream>>>(table, xbuf_hi,
                                        x1a_all + (size_t)i * N, xa2a_all + (size_t)i * N,
                                        h1in, row_ptr, t_sorted,
                                        Whi + (size_t)i * 16384, Wlo + (size_t)i * 16384,
                                        fcsb + (size_t)i * 128, vnext, cvec + (16 + i + 1),
                                        hout, h1out, N);
        table = hout;
        h1in = h1out;
    }

    // fc2
    k_fc2<<<NB64, 256, 0, stream>>>(table, W2hi, W2lo, fc2b, (float*)d_out, N);
}

// Round 15
// 745.982 us; speedup vs baseline: 1.9277x; 1.4801x over previous
//
#include <hip/hip_runtime.h>
#include <math.h>

// ---------------------------------------------------------------------------
// GTAN2 R15: R12 structure (proven 790us) with k_hop BM 64->32 (grid 782->
// 1563): fixes grid starvation (3 blk/CU -> 6, waves/SIMD 3 -> 6) without
// touching per-wave registers (R14's pairing proved ILP-by-register loses).
// Each wave: gathers 8 rows (phase 1), computes 16x64 GEMM sub-tile (phase 2).
// All else byte-identical to R12.
// ---------------------------------------------------------------------------

typedef __attribute__((ext_vector_type(8))) short short8;
typedef __attribute__((ext_vector_type(4))) float f32x4;
#define MFMA16 __builtin_amdgcn_mfma_f32_16x16x32_bf16

__device__ __forceinline__ float lrelu02(float v) { return v > 0.f ? v : 0.2f * v; }

__device__ __forceinline__ float2 bf2f2(unsigned int v) {
    return make_float2(__uint_as_float(v << 16), __uint_as_float(v & 0xffff0000u));
}
__device__ __forceinline__ unsigned int f2bf(float f) {  // RNE bf16
    unsigned int u = __float_as_uint(f);
    u += 0x7fffu + ((u >> 16) & 1u);
    return u >> 16;
}
__device__ __forceinline__ float hi_part(float f) {
    return __uint_as_float(__float_as_uint(f) & 0xffff0000u);
}
__device__ __forceinline__ uint4 pack_hi(const float4& a, const float4& b) {
    uint4 r;
    r.x = (__float_as_uint(a.x) >> 16) | (__float_as_uint(a.y) & 0xffff0000u);
    r.y = (__float_as_uint(a.z) >> 16) | (__float_as_uint(a.w) & 0xffff0000u);
    r.z = (__float_as_uint(b.x) >> 16) | (__float_as_uint(b.y) & 0xffff0000u);
    r.w = (__float_as_uint(b.z) >> 16) | (__float_as_uint(b.w) & 0xffff0000u);
    return r;
}
__device__ __forceinline__ uint4 pack_lo(const float4& a, const float4& b) {
    uint4 r;
    r.x = f2bf(a.x - hi_part(a.x)) | (f2bf(a.y - hi_part(a.y)) << 16);
    r.y = f2bf(a.z - hi_part(a.z)) | (f2bf(a.w - hi_part(a.w)) << 16);
    r.z = f2bf(b.x - hi_part(b.x)) | (f2bf(b.y - hi_part(b.y)) << 16);
    r.w = f2bf(b.z - hi_part(b.z)) | (f2bf(b.w - hi_part(b.w)) << 16);
    return r;
}

// ---------------- CSR build ----------------
__global__ __launch_bounds__(256) void k_count(const int* __restrict__ s, int* __restrict__ cnt, int E) {
    int e = blockIdx.x * 256 + threadIdx.x;
    if (e < E) atomicAdd(&cnt[s[e]], 1);
}

__global__ __launch_bounds__(256) void k_scan1(const int* __restrict__ cnt, int* __restrict__ bs, int N) {
    __shared__ int sh[256];
    int idx = blockIdx.x * 256 + threadIdx.x;
    sh[threadIdx.x] = (idx < N) ? cnt[idx] : 0;
    __syncthreads();
#pragma unroll
    for (int off = 128; off; off >>= 1) {
        if (threadIdx.x < off) sh[threadIdx.x] += sh[threadIdx.x + off];
        __syncthreads();
    }
    if (threadIdx.x == 0) bs[blockIdx.x] = sh[0];
}

__global__ __launch_bounds__(256) void k_scan2(int* __restrict__ bs, int G) {
    __shared__ int sh[256];
    int t = threadIdx.x;
    int v = (t < G) ? bs[t] : 0;
    sh[t] = v;
    __syncthreads();
    int val = v;
#pragma unroll
    for (int off = 1; off < 256; off <<= 1) {
        int o = (t >= off) ? sh[t - off] : 0;
        __syncthreads();
        val += o; sh[t] = val;
        __syncthreads();
    }
    if (t < G) bs[t] = val - v;  // exclusive
}

__global__ __launch_bounds__(256) void k_scan3(const int* __restrict__ cnt, const int* __restrict__ bs,
                                               int* __restrict__ rp, int N) {
    __shared__ int sh[256];
    int t = threadIdx.x;
    int idx = blockIdx.x * 256 + t;
    int v = (idx < N) ? cnt[idx] : 0;
    sh[t] = v;
    __syncthreads();
    int val = v;
#pragma unroll
    for (int off = 1; off < 256; off <<= 1) {
        int o = (t >= off) ? sh[t - off] : 0;
        __syncthreads();
        val += o; sh[t] = val;
        __syncthreads();
    }
    if (idx <= N) rp[idx] = val - v + bs[blockIdx.x];
}

__global__ __launch_bounds__(256) void k_scatter(const int* __restrict__ s, const int* __restrict__ t,
                                                 const int* __restrict__ rp, int* __restrict__ cursor,
                                                 int* __restrict__ t_sorted, int E) {
    int e = blockIdx.x * 256 + threadIdx.x;
    if (e < E) {
        int u = s[e];
        int pos = atomicAdd(&cursor[u], 1);
        t_sorted[rp[u] + pos] = t[e];
    }
}

// ---------------- W split ----------------
__global__ __launch_bounds__(256) void k_wsplit(const float* __restrict__ W,
                                                unsigned short* __restrict__ Whi,
                                                unsigned short* __restrict__ Wlo, int total) {
    int i = blockIdx.x * 256 + threadIdx.x;
    if (i < total) {
        float f = W[i];
        unsigned int u = __float_as_uint(f);
        Whi[i] = (unsigned short)(u >> 16);
        Wlo[i] = (unsigned short)f2bf(f - __uint_as_float(u & 0xffff0000u));
    }
}

// ---------------- k_prep: V vectors (W^T a1, W^T a2) + constants ------------
__global__ __launch_bounds__(256) void k_prep(
    const float* __restrict__ fcsW, const float* __restrict__ fcsb,
    const float* __restrict__ a1, const float* __restrict__ a2,
    float* __restrict__ Vf, unsigned short* __restrict__ Vh,
    unsigned short* __restrict__ Vl, float* __restrict__ cvec) {
    int i = blockIdx.x;
    int t = threadIdx.x;
    const float* W = fcsW + (size_t)i * 16384;
    if (t < 128) {
        float s1 = 0.f, s2 = 0.f;
        for (int j = 0; j < 128; ++j) {
            float w = W[j * 128 + t];
            s1 = fmaf(w, a1[i * 128 + j], s1);
            s2 = fmaf(w, a2[i * 128 + j], s2);
        }
        Vf[i * 128 + t] = s1;
        Vf[(16 + i) * 128 + t] = s2;
        Vh[i * 128 + t] = (unsigned short)(__float_as_uint(s1) >> 16);
        Vl[i * 128 + t] = (unsigned short)f2bf(s1 - hi_part(s1));
        Vh[(16 + i) * 128 + t] = (unsigned short)(__float_as_uint(s2) >> 16);
        Vl[(16 + i) * 128 + t] = (unsigned short)f2bf(s2 - hi_part(s2));
    } else if (t == 128) {
        float c1 = 0.f, c2 = 0.f;
        for (int j = 0; j < 128; ++j) {
            c1 = fmaf(fcsb[i * 128 + j], a1[i * 128 + j], c1);
            c2 = fmaf(fcsb[i * 128 + j], a2[i * 128 + j], c2);
        }
        cvec[i] = c1;
        cvec[16 + i] = c2;
    }
}

// ---------------- fc1: 3-term, BM=64, staged dense stores ----------------
__global__ __launch_bounds__(256) void k_fc1(
    const float* __restrict__ Xf,
    const unsigned short* __restrict__ Wh, const unsigned short* __restrict__ Wl,
    const float* __restrict__ bias,
    unsigned short* __restrict__ Yhi, unsigned short* __restrict__ Ylo, int N) {
    __shared__ unsigned short Shi[64 * 128];
    __shared__ unsigned short Slo[64 * 128];
    const int tid = threadIdx.x;
    const int r0 = blockIdx.x * 64;
    const int lane = tid & 63;
    const int w = tid >> 6;
    const int wr = (w >> 1) * 32, wc = (w & 1) * 64;
    const int frow = lane & 15;
    const int fk = lane >> 4;
    const int q4 = lane >> 4;

    f32x4 acc[2][4];
#pragma unroll
    for (int i = 0; i < 2; ++i)
#pragma unroll
        for (int j = 0; j < 4; ++j) acc[i][j] = (f32x4){0.f, 0.f, 0.f, 0.f};

    const float4 z4 = make_float4(0.f, 0.f, 0.f, 0.f);
#pragma unroll
    for (int kc = 0; kc < 8; ++kc) {
        short8 ah[2], al[2];
#pragma unroll
        for (int ri = 0; ri < 2; ++ri) {
            int row = r0 + wr + ri * 16 + frow;
            float4 va = z4, vb = z4;
            if (row < N) {
                const float* p = Xf + (size_t)row * 256 + kc * 32 + fk * 8;
                va = *(const float4*)p;
                vb = *(const float4*)(p + 4);
            }
            uint4 h = pack_hi(va, vb);
            uint4 l = pack_lo(va, vb);
            ah[ri] = *(short8*)&h;
            al[ri] = *(short8*)&l;
        }
#pragma unroll
        for (int ci = 0; ci < 4; ++ci) {
            int col = wc + ci * 16 + frow;
            short8 bh = *(const short8*)(Wh + (size_t)col * 256 + kc * 32 + fk * 8);
            short8 bl = *(const short8*)(Wl + (size_t)col * 256 + kc * 32 + fk * 8);
#pragma unroll
            for (int ri = 0; ri < 2; ++ri) {
                acc[ri][ci] = MFMA16(ah[ri], bh, acc[ri][ci], 0, 0, 0);
                acc[ri][ci] = MFMA16(ah[ri], bl, acc[ri][ci], 0, 0, 0);
                acc[ri][ci] = MFMA16(al[ri], bh, acc[ri][ci], 0, 0, 0);
            }
        }
    }

#pragma unroll
    for (int ci = 0; ci < 4; ++ci) {
        int col = wc + ci * 16 + frow;
        float bcol = bias[col];
#pragma unroll
        for (int ri = 0; ri < 2; ++ri) {
            f32x4 v = acc[ri][ci];
#pragma unroll
            for (int reg = 0; reg < 4; ++reg) {
                float val = fmaxf(v[reg] + bcol, 0.f);
                int row = wr + ri * 16 + q4 * 4 + reg;
                int dw = (col >> 1) ^ ((row & 12) << 1);
                Shi[row * 128 + dw * 2 + (col & 1)] = (unsigned short)(__float_as_uint(val) >> 16);
                Slo[row * 128 + dw * 2 + (col & 1)] = (unsigned short)f2bf(val - hi_part(val));
            }
        }
    }
    __syncthreads();
#pragma unroll
    for (int q = 0; q < 4; ++q) {
        int idx = q * 256 + tid;
        int row = idx >> 4;
        int gc = idx & 15;
        int dwb = (gc * 4) ^ ((row & 12) << 1);
        int grow = r0 + row;
        if (grow < N) {
            *(uint4*)(Yhi + (size_t)grow * 128 + gc * 8) = *(const uint4*)(Shi + row * 128 + dwb * 2);
            *(uint4*)(Ylo + (size_t)grow * 128 + gc * 8) = *(const uint4*)(Slo + row * 128 + dwb * 2);
        }
    }
}

// ---------------- k_xdots: x1a/xa2a for ALL hops in one N x 32 GEMM ---------
__global__ __launch_bounds__(256) void k_xdots(
    const unsigned short* __restrict__ Xhi, const unsigned short* __restrict__ Xlo,
    const unsigned short* __restrict__ Vh, const unsigned short* __restrict__ Vl,
    const float* __restrict__ cvec,
    float* __restrict__ x1a_all, float* __restrict__ xa2a_all, int N) {
    const int tid = threadIdx.x;
    const int r0 = blockIdx.x * 64;
    const int lane = tid & 63;
    const int w = tid >> 6;
    const int wr = w * 16;
    const int frow = lane & 15;
    const int fk = lane >> 4;
    const int q4 = lane >> 4;

    f32x4 acc[2];
    acc[0] = (f32x4){0.f, 0.f, 0.f, 0.f};
    acc[1] = (f32x4){0.f, 0.f, 0.f, 0.f};

    const short8 z8 = (short8){0, 0, 0, 0, 0, 0, 0, 0};
#pragma unroll
    for (int kc = 0; kc < 4; ++kc) {
        int row = r0 + wr + frow;
        bool ok = row < N;
        short8 ah = ok ? *(const short8*)(Xhi + (size_t)row * 128 + kc * 32 + fk * 8) : z8;
        short8 al = ok ? *(const short8*)(Xlo + (size_t)row * 128 + kc * 32 + fk * 8) : z8;
#pragma unroll
        for (int ci = 0; ci < 2; ++ci) {
            int col = ci * 16 + frow;
            short8 bh = *(const short8*)(Vh + (size_t)col * 128 + kc * 32 + fk * 8);
            short8 bl = *(const short8*)(Vl + (size_t)col * 128 + kc * 32 + fk * 8);
            acc[ci] = MFMA16(ah, bh, acc[ci], 0, 0, 0);
            acc[ci] = MFMA16(ah, bl, acc[ci], 0, 0, 0);
            acc[ci] = MFMA16(al, bh, acc[ci], 0, 0, 0);
        }
    }

#pragma unroll
    for (int ci = 0; ci < 2; ++ci) {
        int col = ci * 16 + frow;
        float c = cvec[col];
#pragma unroll
        for (int reg = 0; reg < 4; ++reg) {
            int grow = r0 + wr + q4 * 4 + reg;
            if (grow < N) {
                float val = acc[ci][reg] + c;
                if (col < 10) x1a_all[(size_t)col * N + grow] = val;
                else if (col >= 16 && col < 26) xa2a_all[(size_t)(col - 16) * N + grow] = val;
            }
        }
    }
}

// ---------------- k_hop: fused gather + GEMM, BM=32 (grid 2x) ---------------
__global__ __launch_bounds__(256) void k_hop(
    const unsigned short* __restrict__ table, const unsigned short* __restrict__ xh,
    const float* __restrict__ x1a, const float* __restrict__ xa2a,
    const float* __restrict__ h1in,
    const int* __restrict__ rp, const int* __restrict__ ts,
    const unsigned short* __restrict__ Wh, const unsigned short* __restrict__ Wl,
    const float* __restrict__ bias, const float* __restrict__ vnext,
    const float* __restrict__ cnextp,
    unsigned short* __restrict__ Hout, float* __restrict__ h1out, int N) {
    __shared__ unsigned short gS[32 * 128];  // 8 KB: g tile, then C-stage
    __shared__ uint2 ew[4][64];
    __shared__ float dotbuf[32][2];
    const int tid = threadIdx.x;
    const int wid = tid >> 6;
    const int lane = tid & 63;
    const int r0 = blockIdx.x * 32;

    // ---- phase 1: each wave gathers 8 rows ----
    for (int j = 0; j < 8; ++j) {
        int gr = wid * 8 + j;
        int u = r0 + gr;
        unsigned int packed = 0u;
        if (u < N) {
            float x1u = x1a[u];
            float w2 = expf(lrelu02(x1u + xa2a[u]));
            float2 xr = bf2f2(*(const unsigned int*)(xh + (size_t)u * 128 + lane * 2));
            float accx = w2 * xr.x, accy = w2 * xr.y;
            float div = w2;
            int p0 = rp[u], p1 = rp[u + 1];
            for (int base = p0; base < p1; base += 64) {
                int e = base + lane;
                uint2 pk = make_uint2(0u, 0u);
                if (e < p1) {
                    int tv = ts[e];
                    pk.x = (unsigned int)tv;
                    pk.y = __float_as_uint(expf(lrelu02(x1u + h1in[tv])));
                }
                ew[wid][lane] = pk;
                int m = p1 - base; if (m > 64) m = 64;
                int m8 = (m + 7) & ~7;
                for (int jj = 0; jj < m8; jj += 8) {
                    uint2 q[8];
#pragma unroll
                    for (int k = 0; k < 8; ++k) q[k] = ew[wid][jj + k];
                    unsigned int hv[8];
#pragma unroll
                    for (int k = 0; k < 8; ++k)
                        hv[k] = *(const unsigned int*)(table + (size_t)q[k].x * 128 + lane * 2);
#pragma unroll
                    for (int k = 0; k < 8; ++k) {
                        float ww = __uint_as_float(q[k].y);
                        float2 f = bf2f2(hv[k]);
                        accx = fmaf(ww, f.x, accx);
                        accy = fmaf(ww, f.y, accy);
                        div += ww;
                    }
                }
            }
            float ox = accx / div, oy = accy / div;
            packed = f2bf(ox) | (f2bf(oy) << 16);
        }
        int dw = (((lane >> 2) ^ (gr & 7)) << 2) | (lane & 3);
        *((unsigned int*)gS + gr * 64 + dw) = packed;
    }
    __syncthreads();

    // ---- phase 2: GEMM (wave = 16 rows x 64 cols) ----
    const int w = wid;
    const int wr = (w >> 1) * 16, wc = (w & 1) * 64;
    const int frow = lane & 15;
    const int fk = lane >> 4;
    const int q4 = lane >> 4;
    const bool dodot = vnext != nullptr;

    f32x4 acc[4];
#pragma unroll
    for (int j = 0; j < 4; ++j) acc[j] = (f32x4){0.f, 0.f, 0.f, 0.f};

#pragma unroll
    for (int kc = 0; kc < 4; ++kc) {
        int row = wr + frow;
        int gg = kc * 4 + fk;
        short8 ah = *(const short8*)(gS + row * 128 + ((gg ^ (row & 7)) * 8));
#pragma unroll
        for (int ci = 0; ci < 4; ++ci) {
            int col = wc + ci * 16 + frow;
            short8 bh = *(const short8*)(Wh + (size_t)col * 128 + kc * 32 + fk * 8);
            short8 bl = *(const short8*)(Wl + (size_t)col * 128 + kc * 32 + fk * 8);
            acc[ci] = MFMA16(ah, bh, acc[ci], 0, 0, 0);
            acc[ci] = MFMA16(ah, bl, acc[ci], 0, 0, 0);
        }
    }
    __syncthreads();  // all A-frag reads done; gS becomes C-stage

    float dotA[4] = {};
#pragma unroll
    for (int ci = 0; ci < 4; ++ci) {
        int col = wc + ci * 16 + frow;
        float bcol = bias[col];
        float vc = dodot ? vnext[col] : 0.f;
        f32x4 v = acc[ci];
#pragma unroll
        for (int reg = 0; reg < 4; ++reg) {
            float val = v[reg] + bcol;
            val = val > 0.f ? val : expf(val) - 1.f;  // elu
            int row = wr + q4 * 4 + reg;
            int dw = (col >> 1) ^ ((row & 12) << 1);
            gS[row * 128 + dw * 2 + (col & 1)] = (unsigned short)f2bf(val);
            dotA[reg] = fmaf(val, vc, dotA[reg]);
        }
    }
#pragma unroll
    for (int m = 1; m < 16; m <<= 1)
#pragma unroll
        for (int reg = 0; reg < 4; ++reg)
            dotA[reg] += __shfl_xor(dotA[reg], m, 64);
    if (frow == 0) {
#pragma unroll
        for (int reg = 0; reg < 4; ++reg) {
            int rl = wr + q4 * 4 + reg;
            dotbuf[rl][w & 1] = dotA[reg];
        }
    }
    __syncthreads();

#pragma unroll
    for (int q = 0; q < 2; ++q) {
        int idx = q * 256 + tid;        // 0..511
        int row = idx >> 4;             // 0..31
        int gc = idx & 15;
        int dwb = (gc * 4) ^ ((row & 12) << 1);
        uint4 vv = *(const uint4*)(gS + row * 128 + dwb * 2);
        int grow = r0 + row;
        if (grow < N) *(uint4*)(Hout + (size_t)grow * 128 + gc * 8) = vv;
    }
    if (dodot && tid < 32) {
        int grow = r0 + tid;
        if (grow < N) h1out[grow] = dotbuf[tid][0] + dotbuf[tid][1] + cnextp[0];
    }
}

// ---------------- fc2: barrier-free, zero-LDS, 2-term, BM=64 ----------------
__global__ __launch_bounds__(256) void k_fc2(
    const unsigned short* __restrict__ Xhi,
    const unsigned short* __restrict__ Wh, const unsigned short* __restrict__ Wl,
    const float* __restrict__ bias, float* __restrict__ Yf, int N) {
    const int tid = threadIdx.x;
    const int r0 = blockIdx.x * 64;
    const int lane = tid & 63;
    const int w = tid >> 6;
    const int wr = w * 16;
    const int frow = lane & 15;
    const int fk = lane >> 4;
    const int q4 = lane >> 4;

    f32x4 acc[4];
#pragma unroll
    for (int j = 0; j < 4; ++j) acc[j] = (f32x4){0.f, 0.f, 0.f, 0.f};

    const short8 z8 = (short8){0, 0, 0, 0, 0, 0, 0, 0};
#pragma unroll
    for (int kc = 0; kc < 4; ++kc) {
        int row = r0 + wr + frow;
        short8 ah = (row < N) ? *(const short8*)(Xhi + (size_t)row * 128 + kc * 32 + fk * 8) : z8;
#pragma unroll
        for (int ci = 0; ci < 4; ++ci) {
            int col = ci * 16 + frow;
            short8 bh = *(const short8*)(Wh + (size_t)col * 128 + kc * 32 + fk * 8);
            short8 bl = *(const short8*)(Wl + (size_t)col * 128 + kc * 32 + fk * 8);
            acc[ci] = MFMA16(ah, bh, acc[ci], 0, 0, 0);
            acc[ci] = MFMA16(ah, bl, acc[ci], 0, 0, 0);
        }
    }

#pragma unroll
    for (int ci = 0; ci < 4; ++ci) {
        int col = ci * 16 + frow;
        float bcol = bias[col];
#pragma unroll
        for (int reg = 0; reg < 4; ++reg) {
            int grow = r0 + wr + q4 * 4 + reg;
            if (grow < N) Yf[(size_t)grow * 64 + col] = acc[ci][reg] + bcol;
        }
    }
}

// ---------------- launch ----------------
extern "C" void kernel_launch(void* const* d_in, const int* in_sizes, int n_in,
                              void* d_out, int out_size, void* d_ws, size_t ws_size,
                              hipStream_t stream) {
    const float* x_in = (const float*)d_in[0];
    const int*   s    = (const int*)d_in[1];
    const int*   t    = (const int*)d_in[2];
    const float* fc1W = (const float*)d_in[3];
    const float* fc1b = (const float*)d_in[4];
    const float* fcsW = (const float*)d_in[5];
    const float* fcsb = (const float*)d_in[6];
    const float* a1   = (const float*)d_in[7];
    const float* a2   = (const float*)d_in[8];
    const float* fc2W = (const float*)d_in[9];
    const float* fc2b = (const float*)d_in[10];

    const int N = in_sizes[0] / 256;  // 50000
    const int E = in_sizes[1];        // 800000
    const int G = (N + 255) / 256;
    const int NB64 = (N + 63) / 64;   // 782
    const int NB32 = (N + 31) / 32;   // 1563

    char* ws = (char*)d_ws;
    size_t off = 0;
    auto alloc = [&](size_t bytes) -> void* {
        void* p = ws + off;
        off += (bytes + 255) & ~(size_t)255;
        return p;
    };
    unsigned short* xbuf_hi = (unsigned short*)alloc((size_t)N * 128 * 2);
    unsigned short* xbuf_lo = (unsigned short*)alloc((size_t)N * 128 * 2);
    unsigned short* hA      = (unsigned short*)alloc((size_t)N * 128 * 2);
    unsigned short* hB      = (unsigned short*)alloc((size_t)N * 128 * 2);
    unsigned short* Whi  = (unsigned short*)alloc((size_t)10 * 16384 * 2);
    unsigned short* Wlo  = (unsigned short*)alloc((size_t)10 * 16384 * 2);
    unsigned short* W1hi = (unsigned short*)alloc((size_t)128 * 256 * 2);
    unsigned short* W1lo = (unsigned short*)alloc((size_t)128 * 256 * 2);
    unsigned short* W2hi = (unsigned short*)alloc((size_t)64 * 128 * 2);
    unsigned short* W2lo = (unsigned short*)alloc((size_t)64 * 128 * 2);
    float* Vf   = (float*)alloc((size_t)32 * 128 * 4);
    unsigned short* Vh = (unsigned short*)alloc((size_t)32 * 128 * 2);
    unsigned short* Vl = (unsigned short*)alloc((size_t)32 * 128 * 2);
    float* cvec = (float*)alloc((size_t)32 * 4);
    float* x1a_all  = (float*)alloc((size_t)10 * N * 4);
    float* xa2a_all = (float*)alloc((size_t)10 * N * 4);
    float* h1aA = (float*)alloc((size_t)N * 4);
    float* h1aB = (float*)alloc((size_t)N * 4);
    int* row_ptr  = (int*)alloc((size_t)(N + 1) * 4);
    int* cnt      = (int*)alloc((size_t)N * 4);
    int* bsums    = (int*)alloc((size_t)1024);
    int* t_sorted = (int*)alloc((size_t)E * 4);

    // CSR build
    hipMemsetAsync(cnt, 0, (size_t)N * 4, stream);
    k_count<<<(E + 255) / 256, 256, 0, stream>>>(s, cnt, E);
    k_scan1<<<G, 256, 0, stream>>>(cnt, bsums, N);
    k_scan2<<<1, 256, 0, stream>>>(bsums, G);
    k_scan3<<<G, 256, 0, stream>>>(cnt, bsums, row_ptr, N);
    hipMemsetAsync(cnt, 0, (size_t)N * 4, stream);
    k_scatter<<<(E + 255) / 256, 256, 0, stream>>>(s, t, row_ptr, cnt, t_sorted, E);

    // W splits + V prep
    k_wsplit<<<(10 * 16384 + 255) / 256, 256, 0, stream>>>(fcsW, Whi, Wlo, 10 * 16384);
    k_wsplit<<<(128 * 256 + 255) / 256, 256, 0, stream>>>(fc1W, W1hi, W1lo, 128 * 256);
    k_wsplit<<<(64 * 128 + 255) / 256, 256, 0, stream>>>(fc2W, W2hi, W2lo, 64 * 128);
    hipMemsetAsync(Vf, 0, (size_t)32 * 128 * 4, stream);
    hipMemsetAsync(Vh, 0, (size_t)32 * 128 * 2, stream);
    hipMemsetAsync(Vl, 0, (size_t)32 * 128 * 2, stream);
    hipMemsetAsync(cvec, 0, (size_t)32 * 4, stream);
    k_prep<<<10, 256, 0, stream>>>(fcsW, fcsb, a1, a2, Vf, Vh, Vl, cvec);

    // fc1 + relu -> split planes
    k_fc1<<<NB64, 256, 0, stream>>>(x_in, W1hi, W1lo, fc1b, xbuf_hi, xbuf_lo, N);

    // x-side scalars for all hops
    k_xdots<<<NB64, 256, 0, stream>>>(xbuf_hi, xbuf_lo, Vh, Vl, cvec,
                                      x1a_all, xa2a_all, N);

    // hops: fused gather + GEMM, ping-pong h / h1a
    const unsigned short* table = xbuf_hi;
    const float* h1in = xa2a_all;  // hop 0: h1 == xa2 (h == x)
    for (int i = 0; i < 10; ++i) {
        unsigned short* hout = (i & 1) ? hB : hA;
        float* h1out = (i & 1) ? h1aB : h1aA;
        const float* vnext = (i < 9) ? (Vf + (size_t)(16 + i + 1) * 128) : nullptr;
        k_hop<<<NB32, 256, 0, stream>>>(table, xbuf_hi,
                                        x1a_all + (size_t)i * N, xa2a_all + (size_t)i * N,
                                        h1in, row_ptr, t_sorted,
                                        Whi + (size_t)i * 16384, Wlo + (size_t)i * 16384,
                                        fcsb + (size_t)i * 128, vnext, cvec + (16 + i + 1),
                                        hout, h1out, N);
        table = hout;
        h1in = h1out;
    }

    // fc2
    k_fc2<<<NB64, 256, 0, stream>>>(table, W2hi, W2lo, fc2b, (float*)d_out, N);
}